// Round 5
// baseline (92.723 us; speedup 1.0000x reference)
//
#include <hip/hip_runtime.h>
#include <math.h>

// Problem constants (from reference)
constexpr int Hr = 64;
constexpr int Wr = 2048;
constexpr int Hb = 512;
constexpr int Wb = 512;
constexpr int B  = 4;
constexpr int C  = 64;
constexpr int BC = B * C;            // 256 channels
constexpr int NPIX = Hb * Wb;        // 262144 pixels

constexpr int T = 8192;              // pixels per tile (per block)
constexpr int G = 8;                 // channels per block
constexpr int NTILE = NPIX / T;      // 32
constexpr int NCG   = BC / G;        // 32

typedef float f32x4 __attribute__((ext_vector_type(4)));
typedef float f32x2 __attribute__((ext_vector_type(2)));

// py = 31.5 exactly -> rows 31,32 with wy = 0.5.
// px in float32: bilinear interp is continuous in px; ~1e-4 px error vs
// numpy's float64 path -> value error ~1e-3 << 0.066 threshold. The phi-wrap
// discontinuity at px=0 is 0.637 px away from the nearest sample point
// (|y|min = 0.5*50/255.5 at 50 m) — float atan2f error cannot cross it,
// so x0 stays in [0, 2046] and x0+1 <= 2047.
//
// LDS layout: buf2[x] = {avg[x], avg[x+1]} so each bilinear gather is ONE
// aligned ds_read_b64 (half the LDS instruction count of two b32 reads).

__global__ __launch_bounds__(256, 4) void rv2bev_fused(
    const float* __restrict__ rv,    // [B][C][Hr][Wr]
    float* __restrict__ out)         // [B][C][Hb][Wb]
{
    __shared__ f32x2 buf2[2][Wr];    // 2 x 16 KB, double-buffered pair-rows

    const int tile = blockIdx.x;     // 0..31
    const int cg   = blockIdx.y;     // 0..31
    const int tid  = threadIdx.x;

    // base of row 31, channel cg*G
    const float* rvb = rv + (size_t)(cg * G) * (Hr * Wr) + (size_t)31 * Wr;

    int   x0t[32];                   // element index into buf2
    float wxt[32];

    // staged global data for the next channel
    f32x4 sa0, sa1, sb0, sb1;
    float se0, se1, se2, se3;

    const int i0 = 4 * tid;          // pair-base for group 0 (tid)
    const int i1 = 4 * (tid + 256);  // pair-base for group 1 (tid+256)

    // issue global loads for channel c (rows 31 and 32 + one overhang scalar each)
    auto issue = [&](int c) {
        const float* chb = rvb + (size_t)c * (Hr * Wr);
        const f32x4* r31 = (const f32x4*)chb;
        const f32x4* r32 = (const f32x4*)(chb + Wr);
        sa0 = r31[tid];       sa1 = r31[tid + 256];
        sb0 = r32[tid];       sb1 = r32[tid + 256];
        se0 = chb[i0 + 4];        // row31 overhang (tid=255,grp1 reads row33[0]: in-bounds, unused)
        se1 = chb[Wr + i0 + 4];   // row32 overhang
        se2 = chb[i1 + 4];
        se3 = chb[Wr + i1 + 4];
    };

    // average + write pair-layout into buf2[nb]
    auto writebuf = [&](int nb) {
        f32x2* d = buf2[nb];
        const f32x4 a0 = sa0 * 0.5f + sb0 * 0.5f;
        const f32x4 a1 = sa1 * 0.5f + sb1 * 0.5f;
        const float n0 = se0 * 0.5f + se1 * 0.5f;
        const float n1 = se2 * 0.5f + se3 * 0.5f;
        d[i0 + 0] = f32x2{a0.x, a0.y};
        d[i0 + 1] = f32x2{a0.y, a0.z};
        d[i0 + 2] = f32x2{a0.z, a0.w};
        d[i0 + 3] = f32x2{a0.w, n0};
        d[i1 + 0] = f32x2{a1.x, a1.y};
        d[i1 + 1] = f32x2{a1.y, a1.z};
        d[i1 + 2] = f32x2{a1.z, a1.w};
        d[i1 + 3] = f32x2{a1.w, n1};
    };

    // ---- prologue: stage channel 0 ----
    issue(0);
    writebuf(0);

    const float cs = 50.0f / 255.5f;                    // R_MAX / (Hb/2 - 0.5)
    const float c1 = 2047.0f / 6.28318530717958647692f; // (Wr-1)/2pi
    const float c2 = 2047.0f / 2048.0f;                 // (Wr-1)/Wr

    #pragma unroll
    for (int c = 0; c < G; ++c) {
        if (c + 1 < G) issue(c + 1);     // T14 issue-early
        __syncthreads();                 // buf2[c&1] staged; prior gathers done

        const f32x2* __restrict__ rowp = buf2[c & 1];
        f32x4* out4 = (f32x4*)(out + (size_t)(cg * G + c) * NPIX + (size_t)tile * T);

        #pragma unroll
        for (int k = 0; k < 8; ++k) {
            f32x4 r;
            #pragma unroll
            for (int j = 0; j < 4; ++j) {
                const int i = k * 4 + j;
                if (c == 0) {
                    // compute px inline (overlaps with ch0's stores), save for c>0
                    const int n  = tile * T + (tid + k * 256) * 4 + j;
                    const float y = ((float)(n >> 9)  - 255.5f) * cs;
                    const float x = ((float)(n & 511) - 255.5f) * cs;
                    float phi = atan2f(y, x);
                    phi = (phi < 0.0f) ? phi + 6.28318530717958647692f : phi;
                    const float px = (2047.0f - phi * c1) * c2;   // in (0, 2046.01)
                    const int   xi = (int)px;                     // px >= 0: trunc == floor
                    x0t[i] = xi;
                    wxt[i] = px - (float)xi;
                }
                const float w = wxt[i];
                const f32x2 v = rowp[x0t[i]];                     // one ds_read_b64
                r[j] = v.x * (1.0f - w) + v.y * w;
            }
            __builtin_nontemporal_store(r, out4 + tid + k * 256);
        }

        if (c + 1 < G) writebuf((c + 1) & 1);   // write-late into other half
    }
}

extern "C" void kernel_launch(void* const* d_in, const int* in_sizes, int n_in,
                              void* d_out, int out_size, void* d_ws, size_t ws_size,
                              hipStream_t stream) {
    const float* rv_feat = (const float*)d_in[0];
    // d_in[1] (ref_bev) is unused by the reference computation.
    float* out = (float*)d_out;

    rv2bev_fused<<<dim3(NTILE, NCG), dim3(256), 0, stream>>>(rv_feat, out);
}

// Round 6
// 59.316 us; speedup vs baseline: 1.5632x; 1.5632x over previous
//
#include <hip/hip_runtime.h>
#include <math.h>

// Problem constants (from reference)
constexpr int Hr = 64;
constexpr int Wr = 2048;
constexpr int Hb = 512;
constexpr int Wb = 512;
constexpr int B  = 4;
constexpr int C  = 64;
constexpr int BC = B * C;            // 256 channels
constexpr int NPIX = Hb * Wb;        // 262144 pixels

constexpr int T = 8192;              // pixels per tile (per block)
constexpr int G = 8;                 // channels per block
constexpr int NTILE = NPIX / T;      // 32
constexpr int NCG   = BC / G;        // 32

typedef float f32x4 __attribute__((ext_vector_type(4)));

// py = 31.5 exactly -> rows 31,32 with wy = 0.5.
// px in float32: bilinear interp is continuous in px; ~1e-4 px error vs
// numpy's float64 path -> value error ~1e-3 << 0.066 threshold. The phi-wrap
// discontinuity at px=0 is ~0.64 px away from the nearest sample point, so
// float atan2f error cannot cross it; x0 in [0,2046], x0+1 <= 2047.

__global__ __launch_bounds__(256) void rv2bev_fused(
    const float* __restrict__ rv,    // [B][C][Hr][Wr]
    float* __restrict__ out)         // [B][C][Hb][Wb]
{
    __shared__ float rowbuf[2][Wr];  // 2 x 8 KB, double-buffered averaged row

    const int tile = blockIdx.x;     // 0..31
    const int cg   = blockIdx.y;     // 0..31
    const int tid  = threadIdx.x;

    int   x0[32];
    float wx[32];

    // base of row 31, channel cg*G
    const float* rvb = rv + (size_t)(cg * G) * (Hr * Wr) + (size_t)31 * Wr;

    f32x4 sa0, sa1, sb0, sb1;        // staged rows for next channel

    // ---- prologue: stage channel 0 into rowbuf[0] ----
    {
        const f32x4* r31 = (const f32x4*)rvb;
        const f32x4* r32 = (const f32x4*)(rvb + Wr);
        sa0 = r31[tid]; sa1 = r31[tid + 256];
        sb0 = r32[tid]; sb1 = r32[tid + 256];
        f32x4* dst = (f32x4*)rowbuf[0];
        dst[tid]       = sa0 * 0.5f + sb0 * 0.5f;
        dst[tid + 256] = sa1 * 0.5f + sb1 * 0.5f;
    }

    const float cs = 50.0f / 255.5f;                    // R_MAX / (Hb/2 - 0.5)
    const float c1 = 2047.0f / 6.28318530717958647692f; // (Wr-1)/2pi
    const float c2 = 2047.0f / 2048.0f;                 // (Wr-1)/Wr

    for (int c = 0; c < G; ++c) {
        // T14 issue-early: launch next channel's global loads before the barrier
        if (c + 1 < G) {
            const float* chb = rvb + (size_t)(c + 1) * (Hr * Wr);
            const f32x4* r31 = (const f32x4*)chb;
            const f32x4* r32 = (const f32x4*)(chb + Wr);
            sa0 = r31[tid]; sa1 = r31[tid + 256];
            sb0 = r32[tid]; sb1 = r32[tid + 256];
        }
        __syncthreads();             // rowbuf[c&1] staged & prior gathers done

        const float* __restrict__ row = rowbuf[c & 1];
        f32x4* out4 = (f32x4*)(out + (size_t)(cg * G + c) * NPIX + (size_t)tile * T);

        if (c == 0) {
            // Channel 0: compute px inline so the atan2f chain overlaps the
            // HBM stores instead of running as a dead upfront phase.
            #pragma unroll
            for (int k = 0; k < 8; ++k) {
                f32x4 r;
                #pragma unroll
                for (int j = 0; j < 4; ++j) {
                    const int i = k * 4 + j;
                    const int n  = tile * T + (tid + k * 256) * 4 + j;
                    const float y = ((float)(n >> 9)  - 255.5f) * cs;
                    const float x = ((float)(n & 511) - 255.5f) * cs;
                    float phi = atan2f(y, x);
                    phi = (phi < 0.0f) ? phi + 6.28318530717958647692f : phi;
                    const float px = (2047.0f - phi * c1) * c2;   // in (0, 2046.01)
                    const float fx = floorf(px);
                    const int   xi = (int)fx;
                    x0[i] = xi;
                    wx[i] = px - fx;
                    const float w = wx[i];
                    r[j] = row[xi] * (1.0f - w) + row[xi + 1] * w;
                }
                __builtin_nontemporal_store(r, out4 + tid + k * 256);
            }
        } else {
            #pragma unroll
            for (int k = 0; k < 8; ++k) {
                f32x4 r;
                #pragma unroll
                for (int j = 0; j < 4; ++j) {
                    const int i = k * 4 + j;
                    const float w = wx[i];
                    r[j] = row[x0[i]] * (1.0f - w) + row[x0[i] + 1] * w;
                }
                __builtin_nontemporal_store(r, out4 + tid + k * 256);
            }
        }

        // write-late: LDS write of next channel after this channel's gathers
        if (c + 1 < G) {
            f32x4* dst = (f32x4*)rowbuf[(c + 1) & 1];
            dst[tid]       = sa0 * 0.5f + sb0 * 0.5f;
            dst[tid + 256] = sa1 * 0.5f + sb1 * 0.5f;
        }
    }
}

extern "C" void kernel_launch(void* const* d_in, const int* in_sizes, int n_in,
                              void* d_out, int out_size, void* d_ws, size_t ws_size,
                              hipStream_t stream) {
    const float* rv_feat = (const float*)d_in[0];
    // d_in[1] (ref_bev) is unused by the reference computation.
    float* out = (float*)d_out;

    rv2bev_fused<<<dim3(NTILE, NCG), dim3(256), 0, stream>>>(rv_feat, out);
}